// Round 8
// baseline (438.333 us; speedup 1.0000x reference)
//
#include <hip/hip_runtime.h>
#include <hip/hip_bf16.h>

// Problem constants: B=2048, L=64, V=4096, D=64, H=8, P=62

typedef __attribute__((ext_vector_type(8))) short short8;
typedef __attribute__((ext_vector_type(4))) float f32x4;

union FragU { uint4 u; short8 v; };

__device__ __forceinline__ unsigned short f2bf(float f) {
    union { float f; unsigned int i; } c; c.f = f;
    unsigned int i = c.i;
    unsigned int r = (i + 0x7fffu + ((i >> 16) & 1u)) >> 16;
    return (unsigned short)r;
}
__device__ __forceinline__ float asf(unsigned int u) {
    union { unsigned int i; float f; } c; c.i = u; return c.f;
}
__device__ __forceinline__ float bfsel(uint2 g, int i) {
    unsigned u = (i < 2) ? g.x : g.y;
    return asf((i & 1) ? (u & 0xffff0000u) : (u << 16));
}
// single-instruction packed f32->bf16 (RTNE), lo -> [15:0], hi -> [31:16]
__device__ __forceinline__ unsigned cvtpk(float lo, float hi) {
    unsigned r;
    asm("v_cvt_pk_bf16_f32 %0, %1, %2" : "=v"(r) : "v"(lo), "v"(hi));
    return r;
}

// xor-1 lane-pair pack: lane holds val[nt] for col 16*nt+c of row `rowptr`
// (36-dword padded LDS rows). Plain [col] u16 order across the 32-dword row.
__device__ __forceinline__ void packstore4(unsigned* rowptr, int c,
                                           float v0, float v1, float v2, float v3) {
    float p0 = __shfl_xor(v0, 1), p1 = __shfl_xor(v1, 1);
    float p2 = __shfl_xor(v2, 1), p3 = __shfl_xor(v3, 1);
    int odd = c & 1;
    float lo0 = odd ? p2 : v0, hi0 = odd ? v2 : p0;
    float lo1 = odd ? p3 : v1, hi1 = odd ? v3 : p1;
    unsigned a0 = cvtpk(lo0, hi0);
    unsigned a1 = cvtpk(lo1, hi1);
    int ba = (c >> 1) + (odd ? 16 : 0);
    rowptr[ba] = a0; rowptr[ba + 8] = a1;
}

// GLOBAL variant: full-64B-line-per-instruction slot mapping.
// store#1 (a0) -> dwords 0..15 (line 0 of the 128B row), store#2 (a1) -> 16..31.
// Stored u16 order within row: [cols 0..15 | 32..47 | 16..31 | 48..63],
// i.e. actual d = m ^ 48 for stored index m in [16,48), identity elsewhere.
__device__ __forceinline__ void packline(unsigned* rowbase, int c,
                                         float v0, float v1, float v2, float v3) {
    float p0 = __shfl_xor(v0, 1), p1 = __shfl_xor(v1, 1);
    float p2 = __shfl_xor(v2, 1), p3 = __shfl_xor(v3, 1);
    int odd = c & 1;
    float lo0 = odd ? p2 : v0, hi0 = odd ? v2 : p0;
    float lo1 = odd ? p3 : v1, hi1 = odd ? v3 : p1;
    unsigned a0 = cvtpk(lo0, hi0);
    unsigned a1 = cvtpk(lo1, hi1);
    int s = (c >> 1) + (odd ? 8 : 0);
    rowbase[s] = a0; rowbase[s + 16] = a1;
}

// ---------------------------------------------------------------------------
// Kernel A: qkv table = W_emb (4096x64) @ W_qkv^T -> bf16 (4096x1536).
// Q-slice (rt<8) pre-scaled by LAM = log2(e)/8 so k_attn's GEMM1 output is
// already log2-scaled (epilogue mul removed there).
// ---------------------------------------------------------------------------
__global__ __launch_bounds__(256) void k_qkv(const float* __restrict__ W_emb,
                                             const float* __restrict__ W_qkv,
                                             unsigned short* __restrict__ qkvb) {
    __shared__ float At[4096];
    __shared__ float Bt[4096];
    int t = threadIdx.x;
    int bt = blockIdx.x / 24, rt = blockIdx.x - bt * 24;
    int r = t >> 2, part = t & 3;
    const float4* esrc = (const float4*)(W_emb + (size_t)((bt << 6) + r) * 64 + part * 16);
    const float4* wsrc = (const float4*)(W_qkv + (size_t)((rt << 6) + r) * 64 + part * 16);
#pragma unroll
    for (int j = 0; j < 4; ++j) {
        float4 e4 = esrc[j], w4 = wsrc[j];
        int c0 = part * 16 + j * 4;
        At[(c0 + 0) * 64 + r] = e4.x; At[(c0 + 1) * 64 + r] = e4.y;
        At[(c0 + 2) * 64 + r] = e4.z; At[(c0 + 3) * 64 + r] = e4.w;
        Bt[(c0 + 0) * 64 + r] = w4.x; Bt[(c0 + 1) * 64 + r] = w4.y;
        Bt[(c0 + 2) * 64 + r] = w4.z; Bt[(c0 + 3) * 64 + r] = w4.w;
    }
    __syncthreads();
    int l0 = (t >> 4) << 2, m0 = (t & 15) << 2;
    float acc[4][4] = {};
#pragma unroll 4
    for (int k = 0; k < 64; ++k) {
        float4 a  = *(const float4*)(At + k * 64 + l0);
        float4 bb = *(const float4*)(Bt + k * 64 + m0);
        float aa[4] = {a.x, a.y, a.z, a.w};
        float bv[4] = {bb.x, bb.y, bb.z, bb.w};
#pragma unroll
        for (int i = 0; i < 4; ++i)
#pragma unroll
            for (int j = 0; j < 4; ++j)
                acc[i][j] = fmaf(aa[i], bv[j], acc[i][j]);
    }
    float qs = (rt < 8) ? 0.18033688f : 1.0f;   // LAM fold into Q slice
#pragma unroll
    for (int i = 0; i < 4; ++i) {
        unsigned w0 = (unsigned)f2bf(acc[i][0] * qs) | ((unsigned)f2bf(acc[i][1] * qs) << 16);
        unsigned w1 = (unsigned)f2bf(acc[i][2] * qs) | ((unsigned)f2bf(acc[i][3] * qs) << 16);
        unsigned* dst = (unsigned*)(qkvb + (size_t)((bt << 6) + l0 + i) * 1536 + (rt << 6) + m0);
        dst[0] = w0; dst[1] = w1;
    }
}

// ---------------------------------------------------------------------------
// Kernel B: trig + W_pos tables, padded 64-col layout, all bf16. Grid = 16.
// ---------------------------------------------------------------------------
__global__ void k_tab(const float* __restrict__ W_pos,
                      unsigned short* __restrict__ cst,
                      unsigned short* __restrict__ csl,
                      unsigned short* __restrict__ wpos) {
    int e = blockIdx.x * 256 + threadIdx.x;
    const float w = 6.283185307179586f / 63.0f;
    int row = e >> 6, col = e & 63;
    {
        int j = col, x = row;
        float val = 0.0f;
        if (j < 31)       val = cosf(w * (float)(((j + 1) * x) % 63));
        else if (j >= 32 && j < 63) val = sinf(w * (float)(((j - 31) * x) % 63));
        cst[e] = f2bf(val);
    }
    {
        int j = row, x = col;
        float val = 0.0f;
        if (j < 31)       val = cosf(w * (float)(((j + 1) * x) % 63));
        else if (j >= 32 && j < 63) val = sinf(w * (float)(((j - 31) * x) % 63));
        csl[e] = f2bf(val);
    }
    {
        int j = row;
        float val = 0.0f;
        if (j < 31) val = W_pos[j * 64 + col];
        else if (j >= 32 && j < 63) val = W_pos[(j - 1) * 64 + col];
        wpos[e] = f2bf(val);
    }
}

// ---------------------------------------------------------------------------
// Kernel C: fused attention — 4-wave variant (r7 + V-scatter fix: jj<8).
// Block = 4 waves = ONE (b,h); wave w4 owns 16-row tile [16*w4, 16*w4+16).
// LDS unchanged (pad-36 rows, 18432 B) -> 8 blocks/CU, 32 waves/CU (8/SIMD).
//   S0: Q -> SC -> ATTN      S1: K -> UW -> V^T
// Ownership: each wave MFMA-A-reads and packstores only its own 16 rows;
// cross-wave reads (K in GEMM1, V^T in GEMM4) sit behind barriers 1 and 3.
// Q pre-scaled by log2(e)/8 in qkvb -> softmax is a bare exp2. Pad tokens
// have zero embeddings -> zero K rows -> sim column exactly 0.
// Output: contiguous [b][h][l][perm-d] bf16 rows, full-64B-line stores.
// ---------------------------------------------------------------------------
__global__ __launch_bounds__(256, 8) void k_attn(
    const int* __restrict__ inputs,
    const unsigned short* __restrict__ qkvb,
    const unsigned short* __restrict__ cstg,
    const unsigned short* __restrict__ cslg,
    const unsigned short* __restrict__ wposg,
    const float* __restrict__ ln_g,
    const float* __restrict__ ln_b,
    unsigned short* __restrict__ out_n)
{
    __shared__ __align__(16) unsigned int smem[4608]; // 18432 B
    unsigned int* S0d = smem;
    unsigned int* S1d = smem + 2304;
    int t = threadIdx.x, w4 = t >> 6, lane = t & 63;
    int b = blockIdx.x >> 3, h = blockIdx.x & 7;
    const int* toks = inputs + b * 64;
    int r = lane & 15, q = lane >> 4, c = r;
    int tk = toks[lane];
    int mt = w4;
    const float INV62 = 1.0f / 62.0f;

    int mk[4]; float gvv[4], bvv[4];
#pragma unroll
    for (int nt = 0; nt < 4; ++nt) {
        mk[nt] = (toks[16 * nt + c] == 0);
        gvv[nt] = ln_g[16 * nt + c];
        bvv[nt] = ln_b[16 * nt + c];
    }

    // ---- gather: threads 0..127 -> Q rows into S0, 128..255 -> K into S1.
    //      Each thread loads one 64B half-row. ----
    {
        int isK = t >> 7;
        int row = (t >> 1) & 63;
        int half = t & 1;
        int tkr = toks[row];
        const uint4* src = (const uint4*)(qkvb + (size_t)tkr * 1536 + (isK ? 512 : 0)
                                          + h * 64 + half * 32);
        uint4* dst = (uint4*)((isK ? S1d : S0d) + row * 36) + half * 4;
#pragma unroll
        for (int j = 0; j < 4; ++j) dst[j] = src[j];
    }
    __syncthreads(); // barrier 1

    f32x4 sc[4], acc[4];
    const f32x4 zf = {0.f, 0.f, 0.f, 0.f};

    // ---- GEMM1: sim = Q K^T (already log2-scaled via Q) ----
#pragma unroll
    for (int nt = 0; nt < 4; ++nt) sc[nt] = zf;
#pragma unroll
    for (int ks = 0; ks < 2; ++ks) {
        FragU Af, Bf[4];
        Af.u = *(const uint4*)(S0d + (16 * mt + r) * 36 + 16 * ks + 4 * q);
#pragma unroll
        for (int nt = 0; nt < 4; ++nt)
            Bf[nt].u = *(const uint4*)(S1d + (16 * nt + r) * 36 + 16 * ks + 4 * q);
#pragma unroll
        for (int nt = 0; nt < 4; ++nt)
            sc[nt] = __builtin_amdgcn_mfma_f32_16x16x32_bf16(Af.v, Bf[nt].v, sc[nt], 0, 0, 0);
    }
    // epilogue 1: pure pack of SC -> S0 own rows
#pragma unroll
    for (int i = 0; i < 4; ++i) {
        int l = 16 * mt + 4 * q + i;
        packstore4(S0d + l * 36, c, sc[0][i], sc[1][i], sc[2][i], sc[3][i]);
    }
    __syncthreads(); // barrier 2

    // ---- GEMM2: pos_w = SC @ Wpos^T + in-reg twist -> UW in S1 own rows ----
#pragma unroll
    for (int nt = 0; nt < 4; ++nt) acc[nt] = zf;
#pragma unroll
    for (int ks = 0; ks < 2; ++ks) {
        FragU Af, Bf[4];
        Af.u = *(const uint4*)(S0d + (16 * mt + r) * 36 + 16 * ks + 4 * q);
#pragma unroll
        for (int nt = 0; nt < 4; ++nt)
            Bf[nt].u = *(const uint4*)(wposg + (16 * nt + r) * 64 + 32 * ks + 8 * q);
#pragma unroll
        for (int nt = 0; nt < 4; ++nt)
            acc[nt] = __builtin_amdgcn_mfma_f32_16x16x32_bf16(Af.v, Bf[nt].v, acc[nt], 0, 0, 0);
    }
    {
        uint2 t00 = *(const uint2*)(cslg + (c) * 64 + 16 * mt + 4 * q);
        uint2 t01 = *(const uint2*)(cslg + (32 + c) * 64 + 16 * mt + 4 * q);
        uint2 t10 = *(const uint2*)(cslg + (16 + c) * 64 + 16 * mt + 4 * q);
        uint2 t11 = *(const uint2*)(cslg + (48 + c) * 64 + 16 * mt + 4 * q);
#pragma unroll
        for (int i = 0; i < 4; ++i) {
            int l = 16 * mt + 4 * q + i;
            float cv0 = bfsel(t00, i), sv0 = bfsel(t01, i);
            float cv1 = bfsel(t10, i), sv1 = bfsel(t11, i);
            float pc0 = acc[0][i], ps0 = acc[2][i];
            float pc1 = acc[1][i], ps1 = acc[3][i];
            float u0 = pc0 * cv0 - ps0 * sv0;
            float u1 = pc1 * cv1 - ps1 * sv1;
            float u2 = pc0 * sv0 + ps0 * cv0;
            float u3 = pc1 * sv1 + ps1 * cv1;
            packstore4(S1d + l * 36, c, u0, u1, u2, u3);
        }
    }

    // ---- GEMM3: bias = UW @ CST^T ----
#pragma unroll
    for (int nt = 0; nt < 4; ++nt) acc[nt] = zf;
#pragma unroll
    for (int ks = 0; ks < 2; ++ks) {
        FragU Af, Bf[4];
        Af.u = *(const uint4*)(S1d + (16 * mt + r) * 36 + 16 * ks + 4 * q);
#pragma unroll
        for (int nt = 0; nt < 4; ++nt)
            Bf[nt].u = *(const uint4*)(cstg + (16 * nt + r) * 64 + 32 * ks + 8 * q);
#pragma unroll
        for (int nt = 0; nt < 4; ++nt)
            acc[nt] = __builtin_amdgcn_mfma_f32_16x16x32_bf16(Af.v, Bf[nt].v, acc[nt], 0, 0, 0);
    }

    // ---- prefetch V quarter-row (own d-quarter, 32 B per lane) ----
    uint4 V4[2];
    {
        const uint4* vsrc = (const uint4*)(qkvb + (size_t)tk * 1536 + 1024 + h * 64 + 16 * w4);
        V4[0] = vsrc[0]; V4[1] = vsrc[1];
    }

    // ---- softmax: x = SC(regs) + bias/62, already log2-scaled -> bare exp2 ----
#pragma unroll
    for (int i = 0; i < 4; ++i) {
        int l = 16 * mt + 4 * q + i;
        float e0 = mk[0] ? 0.f : __builtin_amdgcn_exp2f(fmaf(acc[0][i], INV62, sc[0][i]));
        float e1 = mk[1] ? 0.f : __builtin_amdgcn_exp2f(fmaf(acc[1][i], INV62, sc[1][i]));
        float e2 = mk[2] ? 0.f : __builtin_amdgcn_exp2f(fmaf(acc[2][i], INV62, sc[2][i]));
        float e3 = mk[3] ? 0.f : __builtin_amdgcn_exp2f(fmaf(acc[3][i], INV62, sc[3][i]));
        float s = e0 + e1 + e2 + e3;
        s += __shfl_xor(s, 1);
        s += __shfl_xor(s, 2);
        s += __shfl_xor(s, 4);
        s += __shfl_xor(s, 8);
        float inv = __builtin_amdgcn_rcpf(s);
        packstore4(S0d + l * 36, c, e0 * inv, e1 * inv, e2 * inv, e3 * inv);
    }

    // ---- V^T scatter into S1 own d-quarter rows (8 dwords = 16 d values) ----
    {
        int odd = lane & 1;
        const unsigned* Vd = (const unsigned*)V4;  // 8 dwords: d-pair 16*w4+2jj
#pragma unroll
        for (int jj = 0; jj < 8; ++jj) {
            unsigned my = Vd[jj];
            unsigned pr = __shfl_xor(my, 1);
            unsigned val = odd ? ((pr >> 16) | (my & 0xffff0000u))
                               : ((my & 0xffffu) | (pr << 16));
            S1d[(16 * w4 + 2 * jj + odd) * 36 + (lane >> 1)] = val;
        }
    }
    __syncthreads(); // barrier 3

    // ---- GEMM4: out = ATTN @ V ----
#pragma unroll
    for (int nt = 0; nt < 4; ++nt) acc[nt] = zf;
#pragma unroll
    for (int ks = 0; ks < 2; ++ks) {
        FragU Af, Bf[4];
        Af.u = *(const uint4*)(S0d + (16 * mt + r) * 36 + 16 * ks + 4 * q);
#pragma unroll
        for (int nt = 0; nt < 4; ++nt)
            Bf[nt].u = *(const uint4*)(S1d + (16 * nt + r) * 36 + 16 * ks + 4 * q);
#pragma unroll
        for (int nt = 0; nt < 4; ++nt)
            acc[nt] = __builtin_amdgcn_mfma_f32_16x16x32_bf16(Af.v, Bf[nt].v, acc[nt], 0, 0, 0);
    }
    // ---- LayerNorm + full-line bf16 write to out_n[b][h][l][perm-d] ----
    {
        unsigned* outw = (unsigned*)out_n;
        size_t hb = ((size_t)b * 8 + h) * 64;
#pragma unroll
        for (int i = 0; i < 4; ++i) {
            int l = 16 * mt + 4 * q + i;
            float v0 = acc[0][i], v1 = acc[1][i], v2 = acc[2][i], v3 = acc[3][i];
            float s1 = v0 + v1 + v2 + v3;
            float s2 = v0 * v0 + v1 * v1 + v2 * v2 + v3 * v3;
            s1 += __shfl_xor(s1, 1); s2 += __shfl_xor(s2, 1);
            s1 += __shfl_xor(s1, 2); s2 += __shfl_xor(s2, 2);
            s1 += __shfl_xor(s1, 4); s2 += __shfl_xor(s2, 4);
            s1 += __shfl_xor(s1, 8); s2 += __shfl_xor(s2, 8);
            float mu = s1 * (1.0f / 64.0f);
            float var = s2 * (1.0f / 64.0f) - mu * mu;
            float rstd = __builtin_amdgcn_rsqf(var + 1e-5f);
            float cmu = -mu * rstd;
            float y0 = fmaf(fmaf(v0, rstd, cmu), gvv[0], bvv[0]);
            float y1 = fmaf(fmaf(v1, rstd, cmu), gvv[1], bvv[1]);
            float y2 = fmaf(fmaf(v2, rstd, cmu), gvv[2], bvv[2]);
            float y3 = fmaf(fmaf(v3, rstd, cmu), gvv[3], bvv[3]);
            packline(outw + (hb + l) * 32, c, y0, y1, y2, y3);
        }
    }
}

// ---------------------------------------------------------------------------
// Kernel D (MFMA): per b. Stage 16-l chunks of out_n[b][h][l][perm-d] into LDS
// transposed as XT[l][d][h] (pad 8, perm-d undone via m^48 block remap).
// Staging: xor-pair dword packing + next-chunk register prefetch.
// C_l[d][o] = X_l[d,h] @ W1^T (K=8 pad 32, b1 folded into k=8 slot).
// g[b,d,o] = (1/cnt) * sum_{valid l} relu(C_l). 4 waves = quadrants.
// ---------------------------------------------------------------------------
__global__ __launch_bounds__(256) void k_mlp(const int* __restrict__ inputs,
                                             const unsigned short* __restrict__ out_n,
                                             const float* __restrict__ W1,
                                             const float* __restrict__ b1,
                                             float* __restrict__ gws) {
    __shared__ unsigned short XT[8320]; // 16 rows * 520 u16 (row pad 8)
    __shared__ unsigned long long vmask_s;
    __shared__ float invcnt_s;
    int t = threadIdx.x, w = t >> 6, lane = t & 63;
    int b = blockIdx.x;
    int ot = w >> 1, dt = w & 1;
    int kq = lane >> 4, n = lane & 15;

    if (t < 64) {
        int tok = inputs[b * 64 + t];
        unsigned long long bal = __ballot(tok != 0);
        if (t == 0) {
            int cnt = __popcll(bal);
            if (cnt < 1) cnt = 1;
            vmask_s = bal;
            invcnt_s = 1.0f / (float)cnt;
        }
    }

    // B-frags: W1 rows o = 32*ot + 16*om + n, k=h on kq==0 lanes; k=8 -> b1[o]
    FragU Wf[2];
#pragma unroll
    for (int om = 0; om < 2; ++om) {
        int o = 32 * ot + 16 * om + n;
        if (kq == 0) {
            const float4* wsrc = (const float4*)(W1 + o * 8);
            float4 wa = wsrc[0], wb = wsrc[1];
            Wf[om].u.x = (unsigned)f2bf(wa.x) | ((unsigned)f2bf(wa.y) << 16);
            Wf[om].u.y = (unsigned)f2bf(wa.z) | ((unsigned)f2bf(wa.w) << 16);
            Wf[om].u.z = (unsigned)f2bf(wb.x) | ((unsigned)f2bf(wb.y) << 16);
            Wf[om].u.w = (unsigned)f2bf(wb.z) | ((unsigned)f2bf(wb.w) << 16);
        } else if (kq == 1) {
            Wf[om].u = make_uint4((unsigned)f2bf(b1[o]), 0, 0, 0); // B[8][o] = b1[o]
        } else {
            Wf[om].u = make_uint4(0, 0, 0, 0);
        }
    }

    f32x4 racc[2][2];
    const f32x4 zf = {0.f, 0.f, 0.f, 0.f};
#pragma unroll
    for (int dm = 0; dm < 2; ++dm)
#pragma unroll
        for (int om = 0; om < 2; ++om) racc[dm][om] = zf;

    int lh = t & 7;          // h for the load phase
    int lr = (t >> 3) & 15;  // l-within-chunk
    int half = t >> 7;       // stored-d half

    // per-thread base of its load stream; chunk cc = +cc*128 uint4
    const uint4* src4 = (const uint4*)(out_n + (size_t)b * 32768 + lh * 4096
                                       + lr * 64 + half * 32);
    uint4 G[4], Gn[4];
#pragma unroll
    for (int j = 0; j < 4; ++j) G[j] = src4[j];   // prefetch chunk 0

    int c2 = lh >> 1, lodd = lh & 1;
    unsigned* XTd = (unsigned*)XT;
    int dbase = lr * 260 + c2;

    __syncthreads();
    unsigned long long vmask = vmask_s;
    float invcnt = invcnt_s;

    for (int cc = 0; cc < 4; ++cc) {
        __syncthreads(); // previous chunk's compute done before overwrite
        // ---- stage G -> XT via xor-pair dword packing ----
#pragma unroll
        for (int j = 0; j < 4; ++j) {
            int m0 = half * 32 + j * 8;                       // stored index
            int d0 = (m0 >= 16 && m0 < 48) ? (m0 ^ 48) : m0;  // actual d
            unsigned wv[4] = {G[j].x, G[j].y, G[j].z, G[j].w};
#pragma unroll
            for (int i = 0; i < 4; ++i) {
                unsigned pw = __shfl_xor(wv[i], 1);
                unsigned val = lodd ? ((pw >> 16) | (wv[i] & 0xffff0000u))
                                    : ((wv[i] & 0xffffu) | (pw << 16));
                int d = d0 + 2 * i + lodd;
                XTd[dbase + d * 4] = val;
            }
        }
        // ---- prefetch next chunk (hides L2/L3 latency under compute) ----
        if (cc < 3) {
#pragma unroll
            for (int j = 0; j < 4; ++j) Gn[j] = src4[(cc + 1) * 128 + j];
        }
        __syncthreads();
#pragma unroll 4
        for (int l = 0; l < 16; ++l) {
            if (!((vmask >> (16 * cc + l)) & 1ull)) continue; // pad token: skip (uniform)
            FragU Xf[2];
#pragma unroll
            for (int dm = 0; dm < 2; ++dm) {
                if (kq == 0)
                    Xf[dm].u = *(const uint4*)(XT + l * 520 + (32 * dt + 16 * dm + n) * 8);
                else if (kq == 1)
                    Xf[dm].u = make_uint4(0x3F80u, 0, 0, 0);  // A[d][8] = 1.0
                else
                    Xf[dm].u = make_uint4(0, 0, 0, 0);
            }
#pragma unroll
            for (int dm = 0; dm < 2; ++dm)
#pragma unroll
                for (int om = 0; om < 2; ++om) {
                    f32x4 C = __builtin_amdgcn_mfma_f32_16x16x32_bf16(Xf[dm].v, Wf[om].v, zf, 0, 0, 0);
#pragma unroll
                    for (int i = 0; i < 4; ++i)
                        racc[dm][om][i] += fmaxf(C[i], 0.0f);
                }
        }
        if (cc < 3) {
#pragma unroll
            for (int j = 0; j < 4; ++j) G[j] = Gn[j];
        }
    }
    // store: row d = 32dt+16dm+4*kq+i, col o = 32ot+16om+n
    float* gb = gws + (size_t)b * 4096;
#pragma unroll
    for (int dm = 0; dm < 2; ++dm)
#pragma unroll
        for (int om = 0; om < 2; ++om) {
            int o = 32 * ot + 16 * om + n;
#pragma unroll
            for (int i = 0; i < 4; ++i) {
                int d = 32 * dt + 16 * dm + 4 * kq + i;
                gb[d * 64 + o] = racc[dm][om][i] * invcnt;
            }
        }
}

// ---------------------------------------------------------------------------
// Kernel E: per name n: gbar = mean over 4 words; out = W2 @ gbar + b2
// ---------------------------------------------------------------------------
__global__ __launch_bounds__(256) void k_final(const float* __restrict__ gws,
                                               const float* __restrict__ W2,
                                               const float* __restrict__ b2,
                                               float* __restrict__ out) {
    __shared__ float gbar[4096];
    __shared__ float w2s[32 * 68];
    __shared__ float b2s[32];
    int t = threadIdx.x;
    int n = blockIdx.x;
    for (int e = t; e < 4096; e += 256) {
        size_t base = (size_t)(4 * n) * 4096 + e;
        gbar[e] = 0.25f * (gws[base] + gws[base + 4096] + gws[base + 8192] + gws[base + 12288]);
    }
    for (int e = t; e < 2048; e += 256) {
        int p = e >> 6, o = e & 63;
        w2s[p * 68 + o] = W2[e];
    }
    if (t < 32) b2s[t] = b2[t];
    __syncthreads();
#pragma unroll
    for (int jj = 0; jj < 8; ++jj) {
        int f = jj * 256 + t;
        int d = f >> 5, p = f & 31;
        float acc = b2s[p];
        for (int o4 = 0; o4 < 16; ++o4) {
            float4 gvv = *(const float4*)(gbar + d * 64 + o4 * 4);
            float4 wv = *(const float4*)(w2s + p * 68 + o4 * 4);
            acc = fmaf(gvv.x, wv.x, acc);
            acc = fmaf(gvv.y, wv.y, acc);
            acc = fmaf(gvv.z, wv.z, acc);
            acc = fmaf(gvv.w, wv.w, acc);
        }
        out[(size_t)n * 2048 + f] = acc;
    }
}

// ---------------------------------------------------------------------------
extern "C" void kernel_launch(void* const* d_in, const int* in_sizes, int n_in,
                              void* d_out, int out_size, void* d_ws, size_t ws_size,
                              hipStream_t stream) {
    const int*   inputs = (const int*)d_in[0];
    const float* W_emb  = (const float*)d_in[1];
    const float* W_qkv  = (const float*)d_in[2];
    const float* W_pos  = (const float*)d_in[3];
    const float* ln_g   = (const float*)d_in[4];
    const float* ln_b   = (const float*)d_in[5];
    const float* W1     = (const float*)d_in[6];
    const float* b1     = (const float*)d_in[7];
    const float* W2     = (const float*)d_in[8];
    const float* b2     = (const float*)d_in[9];
    float* out = (float*)d_out;

    // ws layout (u16 units unless noted): qkvb 6291456 | cst 4096 | csl 4096 |
    // wpos 4096 | gws fp32 8388608 | out_n u16 67108864
    unsigned short* qkvb = (unsigned short*)d_ws;
    unsigned short* cst  = qkvb + 6291456;
    unsigned short* csl  = cst + 4096;
    unsigned short* wpos = csl + 4096;
    float* gws = (float*)(wpos + 4096);
    unsigned short* out_n = (unsigned short*)(gws + 8388608);

    hipLaunchKernelGGL(k_qkv,   dim3(64 * 24), dim3(256), 0, stream, W_emb, W_qkv, qkvb);
    hipLaunchKernelGGL(k_tab,   dim3(16),      dim3(256), 0, stream, W_pos, cst, csl, wpos);
    hipLaunchKernelGGL(k_attn,  dim3(16384),   dim3(256), 0, stream,
                       inputs, qkvb, cst, csl, wpos, ln_g, ln_b, out_n);
    hipLaunchKernelGGL(k_mlp,   dim3(2048),    dim3(256), 0, stream, inputs, out_n, W1, b1, gws);
    hipLaunchKernelGGL(k_final, dim3(512),     dim3(256), 0, stream, gws, W2, b2, out);
}

// Round 9
// 356.958 us; speedup vs baseline: 1.2280x; 1.2280x over previous
//
#include <hip/hip_runtime.h>
#include <hip/hip_bf16.h>

// Problem constants: B=2048, L=64, V=4096, D=64, H=8, P=62

typedef __attribute__((ext_vector_type(8))) short short8;
typedef __attribute__((ext_vector_type(4))) float f32x4;

union FragU { uint4 u; short8 v; };

__device__ __forceinline__ unsigned short f2bf(float f) {
    union { float f; unsigned int i; } c; c.f = f;
    unsigned int i = c.i;
    unsigned int r = (i + 0x7fffu + ((i >> 16) & 1u)) >> 16;
    return (unsigned short)r;
}
__device__ __forceinline__ float asf(unsigned int u) {
    union { unsigned int i; float f; } c; c.i = u; return c.f;
}
__device__ __forceinline__ float bfsel(uint2 g, int i) {
    unsigned u = (i < 2) ? g.x : g.y;
    return asf((i & 1) ? (u & 0xffff0000u) : (u << 16));
}
// single-instruction packed f32->bf16 (RTNE), lo -> [15:0], hi -> [31:16]
__device__ __forceinline__ unsigned cvtpk(float lo, float hi) {
    unsigned r;
    asm("v_cvt_pk_bf16_f32 %0, %1, %2" : "=v"(r) : "v"(lo), "v"(hi));
    return r;
}

// xor-1 lane-pair pack: lane holds val[nt] for col 16*nt+c of row `rowptr`
// (36-dword padded LDS rows). Plain [col] u16 order across the 32-dword row.
__device__ __forceinline__ void packstore4(unsigned* rowptr, int c,
                                           float v0, float v1, float v2, float v3) {
    float p0 = __shfl_xor(v0, 1), p1 = __shfl_xor(v1, 1);
    float p2 = __shfl_xor(v2, 1), p3 = __shfl_xor(v3, 1);
    int odd = c & 1;
    float lo0 = odd ? p2 : v0, hi0 = odd ? v2 : p0;
    float lo1 = odd ? p3 : v1, hi1 = odd ? v3 : p1;
    unsigned a0 = cvtpk(lo0, hi0);
    unsigned a1 = cvtpk(lo1, hi1);
    int ba = (c >> 1) + (odd ? 16 : 0);
    rowptr[ba] = a0; rowptr[ba + 8] = a1;
}

// GLOBAL variant: full-64B-line-per-instruction slot mapping.
// store#1 (a0) -> dwords 0..15 (line 0 of the 128B row), store#2 (a1) -> 16..31.
// Stored u16 order within row: [cols 0..15 | 32..47 | 16..31 | 48..63],
// i.e. actual d = m ^ 48 for stored index m in [16,48), identity elsewhere.
__device__ __forceinline__ void packline(unsigned* rowbase, int c,
                                         float v0, float v1, float v2, float v3) {
    float p0 = __shfl_xor(v0, 1), p1 = __shfl_xor(v1, 1);
    float p2 = __shfl_xor(v2, 1), p3 = __shfl_xor(v3, 1);
    int odd = c & 1;
    float lo0 = odd ? p2 : v0, hi0 = odd ? v2 : p0;
    float lo1 = odd ? p3 : v1, hi1 = odd ? v3 : p1;
    unsigned a0 = cvtpk(lo0, hi0);
    unsigned a1 = cvtpk(lo1, hi1);
    int s = (c >> 1) + (odd ? 8 : 0);
    rowbase[s] = a0; rowbase[s + 16] = a1;
}

// ---------------------------------------------------------------------------
// Kernel A: qkv table = W_emb (4096x64) @ W_qkv^T -> bf16 (4096x1536).
// Q-slice (rt<8) pre-scaled by LAM = log2(e)/8 so k_attn's GEMM1 output is
// already log2-scaled (epilogue mul removed there).
// ---------------------------------------------------------------------------
__global__ __launch_bounds__(256) void k_qkv(const float* __restrict__ W_emb,
                                             const float* __restrict__ W_qkv,
                                             unsigned short* __restrict__ qkvb) {
    __shared__ float At[4096];
    __shared__ float Bt[4096];
    int t = threadIdx.x;
    int bt = blockIdx.x / 24, rt = blockIdx.x - bt * 24;
    int r = t >> 2, part = t & 3;
    const float4* esrc = (const float4*)(W_emb + (size_t)((bt << 6) + r) * 64 + part * 16);
    const float4* wsrc = (const float4*)(W_qkv + (size_t)((rt << 6) + r) * 64 + part * 16);
#pragma unroll
    for (int j = 0; j < 4; ++j) {
        float4 e4 = esrc[j], w4 = wsrc[j];
        int c0 = part * 16 + j * 4;
        At[(c0 + 0) * 64 + r] = e4.x; At[(c0 + 1) * 64 + r] = e4.y;
        At[(c0 + 2) * 64 + r] = e4.z; At[(c0 + 3) * 64 + r] = e4.w;
        Bt[(c0 + 0) * 64 + r] = w4.x; Bt[(c0 + 1) * 64 + r] = w4.y;
        Bt[(c0 + 2) * 64 + r] = w4.z; Bt[(c0 + 3) * 64 + r] = w4.w;
    }
    __syncthreads();
    int l0 = (t >> 4) << 2, m0 = (t & 15) << 2;
    float acc[4][4] = {};
#pragma unroll 4
    for (int k = 0; k < 64; ++k) {
        float4 a  = *(const float4*)(At + k * 64 + l0);
        float4 bb = *(const float4*)(Bt + k * 64 + m0);
        float aa[4] = {a.x, a.y, a.z, a.w};
        float bv[4] = {bb.x, bb.y, bb.z, bb.w};
#pragma unroll
        for (int i = 0; i < 4; ++i)
#pragma unroll
            for (int j = 0; j < 4; ++j)
                acc[i][j] = fmaf(aa[i], bv[j], acc[i][j]);
    }
    float qs = (rt < 8) ? 0.18033688f : 1.0f;   // LAM fold into Q slice
#pragma unroll
    for (int i = 0; i < 4; ++i) {
        unsigned w0 = (unsigned)f2bf(acc[i][0] * qs) | ((unsigned)f2bf(acc[i][1] * qs) << 16);
        unsigned w1 = (unsigned)f2bf(acc[i][2] * qs) | ((unsigned)f2bf(acc[i][3] * qs) << 16);
        unsigned* dst = (unsigned*)(qkvb + (size_t)((bt << 6) + l0 + i) * 1536 + (rt << 6) + m0);
        dst[0] = w0; dst[1] = w1;
    }
}

// ---------------------------------------------------------------------------
// Kernel B: trig + W_pos tables, padded 64-col layout, all bf16. Grid = 16.
// ---------------------------------------------------------------------------
__global__ void k_tab(const float* __restrict__ W_pos,
                      unsigned short* __restrict__ cst,
                      unsigned short* __restrict__ csl,
                      unsigned short* __restrict__ wpos) {
    int e = blockIdx.x * 256 + threadIdx.x;
    const float w = 6.283185307179586f / 63.0f;
    int row = e >> 6, col = e & 63;
    {
        int j = col, x = row;
        float val = 0.0f;
        if (j < 31)       val = cosf(w * (float)(((j + 1) * x) % 63));
        else if (j >= 32 && j < 63) val = sinf(w * (float)(((j - 31) * x) % 63));
        cst[e] = f2bf(val);
    }
    {
        int j = row, x = col;
        float val = 0.0f;
        if (j < 31)       val = cosf(w * (float)(((j + 1) * x) % 63));
        else if (j >= 32 && j < 63) val = sinf(w * (float)(((j - 31) * x) % 63));
        csl[e] = f2bf(val);
    }
    {
        int j = row;
        float val = 0.0f;
        if (j < 31) val = W_pos[j * 64 + col];
        else if (j >= 32 && j < 63) val = W_pos[(j - 1) * 64 + col];
        wpos[e] = f2bf(val);
    }
}

// ---------------------------------------------------------------------------
// Kernel C: fused attention (r5 2-wave checkpoint + s_setprio around MFMA
// clusters). Block = 2 waves = ONE (b,h); wave w2 owns row-half
// [32*w2, 32*w2+32). Pad-36 LDS rows, 18432 B -> 8 blocks/CU; VGPR-capped
// at 4 waves/SIMD (r8 showed 8 waves/SIMD forces spills — do not raise).
//   S0: Q -> SC -> ATTN      S1: K -> UW -> V^T
// Q pre-scaled by log2(e)/8 in qkvb -> GEMM1 output log2-scaled, softmax is
// a bare exp2. Pad tokens have zero embeddings -> zero K rows -> sim col 0.
// setprio(1) around MFMA: 8 independent blocks/CU at different phases ->
// scheduler favors MFMA-issuing waves (attn regime, m191).
// Output: contiguous [b][h][l][perm-d] bf16 rows, full-64B-line stores.
// ---------------------------------------------------------------------------
__global__ __launch_bounds__(128, 4) void k_attn(
    const int* __restrict__ inputs,
    const unsigned short* __restrict__ qkvb,
    const unsigned short* __restrict__ cstg,
    const unsigned short* __restrict__ cslg,
    const unsigned short* __restrict__ wposg,
    const float* __restrict__ ln_g,
    const float* __restrict__ ln_b,
    unsigned short* __restrict__ out_n)
{
    __shared__ __align__(16) unsigned int smem[4608]; // 18432 B
    unsigned int* S0d = smem;
    unsigned int* S1d = smem + 2304;
    int t = threadIdx.x, w2 = t >> 6, lane = t & 63;
    int b = blockIdx.x >> 3, h = blockIdx.x & 7;
    const int* toks = inputs + b * 64;
    int r = lane & 15, q = lane >> 4, c = r;
    int tk = toks[lane];
    int mt0 = 2 * w2;
    const float INV62 = 1.0f / 62.0f;

    int mk[4]; float gvv[4], bvv[4];
#pragma unroll
    for (int nt = 0; nt < 4; ++nt) {
        mk[nt] = (toks[16 * nt + c] == 0);
        gvv[nt] = ln_g[16 * nt + c];
        bvv[nt] = ln_b[16 * nt + c];
    }

    // ---- gather: wave0 -> Q into S0, wave1 -> K into S1 (lane = row) ----
    {
        const uint4* src = (const uint4*)(qkvb + (size_t)tk * 1536 + (w2 ? 512 : 0) + h * 64);
        uint4* dst = (uint4*)((w2 ? S1d : S0d) + lane * 36);
#pragma unroll
        for (int j = 0; j < 8; ++j) dst[j] = src[j];
    }
    __syncthreads(); // barrier 1

    f32x4 sc[2][4], acc[2][4];
    const f32x4 zf = {0.f, 0.f, 0.f, 0.f};

    // ---- GEMM1: sim = Q K^T (already log2-scaled via Q) ----
#pragma unroll
    for (int u = 0; u < 2; ++u)
#pragma unroll
        for (int nt = 0; nt < 4; ++nt) sc[u][nt] = zf;
#pragma unroll
    for (int ks = 0; ks < 2; ++ks) {
        FragU Af[2], Bf[4];
#pragma unroll
        for (int u = 0; u < 2; ++u)
            Af[u].u = *(const uint4*)(S0d + (16 * (mt0 + u) + r) * 36 + 16 * ks + 4 * q);
#pragma unroll
        for (int nt = 0; nt < 4; ++nt)
            Bf[nt].u = *(const uint4*)(S1d + (16 * nt + r) * 36 + 16 * ks + 4 * q);
        __builtin_amdgcn_s_setprio(1);
#pragma unroll
        for (int u = 0; u < 2; ++u)
#pragma unroll
            for (int nt = 0; nt < 4; ++nt)
                sc[u][nt] = __builtin_amdgcn_mfma_f32_16x16x32_bf16(Af[u].v, Bf[nt].v, sc[u][nt], 0, 0, 0);
        __builtin_amdgcn_s_setprio(0);
    }
    // epilogue 1: pure pack of SC -> S0 own rows (no mask/scale needed)
#pragma unroll
    for (int u = 0; u < 2; ++u)
#pragma unroll
        for (int i = 0; i < 4; ++i) {
            int l = 16 * (mt0 + u) + 4 * q + i;
            packstore4(S0d + l * 36, c, sc[u][0][i], sc[u][1][i], sc[u][2][i], sc[u][3][i]);
        }
    __syncthreads(); // barrier 2

    // ---- GEMM2: pos_w = SC @ Wpos^T + in-reg twist -> UW in S1 own rows ----
#pragma unroll
    for (int u = 0; u < 2; ++u)
#pragma unroll
        for (int nt = 0; nt < 4; ++nt) acc[u][nt] = zf;
#pragma unroll
    for (int ks = 0; ks < 2; ++ks) {
        FragU Af[2], Bf[4];
#pragma unroll
        for (int u = 0; u < 2; ++u)
            Af[u].u = *(const uint4*)(S0d + (16 * (mt0 + u) + r) * 36 + 16 * ks + 4 * q);
#pragma unroll
        for (int nt = 0; nt < 4; ++nt)
            Bf[nt].u = *(const uint4*)(wposg + (16 * nt + r) * 64 + 32 * ks + 8 * q);
        __builtin_amdgcn_s_setprio(1);
#pragma unroll
        for (int u = 0; u < 2; ++u)
#pragma unroll
            for (int nt = 0; nt < 4; ++nt)
                acc[u][nt] = __builtin_amdgcn_mfma_f32_16x16x32_bf16(Af[u].v, Bf[nt].v, acc[u][nt], 0, 0, 0);
        __builtin_amdgcn_s_setprio(0);
    }
#pragma unroll
    for (int u = 0; u < 2; ++u) {
        int mt = mt0 + u;
        uint2 t00 = *(const uint2*)(cslg + (c) * 64 + 16 * mt + 4 * q);
        uint2 t01 = *(const uint2*)(cslg + (32 + c) * 64 + 16 * mt + 4 * q);
        uint2 t10 = *(const uint2*)(cslg + (16 + c) * 64 + 16 * mt + 4 * q);
        uint2 t11 = *(const uint2*)(cslg + (48 + c) * 64 + 16 * mt + 4 * q);
#pragma unroll
        for (int i = 0; i < 4; ++i) {
            int l = 16 * mt + 4 * q + i;
            float cv0 = bfsel(t00, i), sv0 = bfsel(t01, i);
            float cv1 = bfsel(t10, i), sv1 = bfsel(t11, i);
            float pc0 = acc[u][0][i], ps0 = acc[u][2][i];
            float pc1 = acc[u][1][i], ps1 = acc[u][3][i];
            float u0 = pc0 * cv0 - ps0 * sv0;
            float u1 = pc1 * cv1 - ps1 * sv1;
            float u2 = pc0 * sv0 + ps0 * cv0;
            float u3 = pc1 * sv1 + ps1 * cv1;
            packstore4(S1d + l * 36, c, u0, u1, u2, u3);
        }
    }

    // ---- GEMM3: bias = UW @ CST^T ----
#pragma unroll
    for (int u = 0; u < 2; ++u)
#pragma unroll
        for (int nt = 0; nt < 4; ++nt) acc[u][nt] = zf;
#pragma unroll
    for (int ks = 0; ks < 2; ++ks) {
        FragU Af[2], Bf[4];
#pragma unroll
        for (int u = 0; u < 2; ++u)
            Af[u].u = *(const uint4*)(S1d + (16 * (mt0 + u) + r) * 36 + 16 * ks + 4 * q);
#pragma unroll
        for (int nt = 0; nt < 4; ++nt)
            Bf[nt].u = *(const uint4*)(cstg + (16 * nt + r) * 64 + 32 * ks + 8 * q);
        __builtin_amdgcn_s_setprio(1);
#pragma unroll
        for (int u = 0; u < 2; ++u)
#pragma unroll
            for (int nt = 0; nt < 4; ++nt)
                acc[u][nt] = __builtin_amdgcn_mfma_f32_16x16x32_bf16(Af[u].v, Bf[nt].v, acc[u][nt], 0, 0, 0);
        __builtin_amdgcn_s_setprio(0);
    }

    // ---- prefetch V half-row (own d-half, 64 B per lane) ----
    uint4 V4[4];
    {
        const uint4* vsrc = (const uint4*)(qkvb + (size_t)tk * 1536 + 1024 + h * 64 + 32 * w2);
#pragma unroll
        for (int j = 0; j < 4; ++j) V4[j] = vsrc[j];
    }

    // ---- softmax: x = SC(regs) + bias/62, already log2-scaled -> bare exp2 ----
#pragma unroll
    for (int u = 0; u < 2; ++u)
#pragma unroll
        for (int i = 0; i < 4; ++i) {
            int l = 16 * (mt0 + u) + 4 * q + i;
            float e0 = mk[0] ? 0.f : __builtin_amdgcn_exp2f(fmaf(acc[u][0][i], INV62, sc[u][0][i]));
            float e1 = mk[1] ? 0.f : __builtin_amdgcn_exp2f(fmaf(acc[u][1][i], INV62, sc[u][1][i]));
            float e2 = mk[2] ? 0.f : __builtin_amdgcn_exp2f(fmaf(acc[u][2][i], INV62, sc[u][2][i]));
            float e3 = mk[3] ? 0.f : __builtin_amdgcn_exp2f(fmaf(acc[u][3][i], INV62, sc[u][3][i]));
            float s = e0 + e1 + e2 + e3;
            s += __shfl_xor(s, 1);
            s += __shfl_xor(s, 2);
            s += __shfl_xor(s, 4);
            s += __shfl_xor(s, 8);
            float inv = __builtin_amdgcn_rcpf(s);
            packstore4(S0d + l * 36, c, e0 * inv, e1 * inv, e2 * inv, e3 * inv);
        }

    // ---- V^T scatter into S1 own d-half rows ----
    {
        int odd = lane & 1;
        const unsigned* Vd = (const unsigned*)V4;
#pragma unroll
        for (int jj = 0; jj < 16; ++jj) {
            unsigned my = Vd[jj];
            unsigned pr = __shfl_xor(my, 1);
            unsigned val = odd ? ((pr >> 16) | (my & 0xffff0000u))
                               : ((my & 0xffffu) | (pr << 16));
            S1d[(32 * w2 + 2 * jj + odd) * 36 + (lane >> 1)] = val;
        }
    }
    __syncthreads(); // barrier 3

    // ---- GEMM4: out = ATTN @ V ----
#pragma unroll
    for (int u = 0; u < 2; ++u)
#pragma unroll
        for (int nt = 0; nt < 4; ++nt) acc[u][nt] = zf;
#pragma unroll
    for (int ks = 0; ks < 2; ++ks) {
        FragU Af[2], Bf[4];
#pragma unroll
        for (int u = 0; u < 2; ++u)
            Af[u].u = *(const uint4*)(S0d + (16 * (mt0 + u) + r) * 36 + 16 * ks + 4 * q);
#pragma unroll
        for (int nt = 0; nt < 4; ++nt)
            Bf[nt].u = *(const uint4*)(S1d + (16 * nt + r) * 36 + 16 * ks + 4 * q);
        __builtin_amdgcn_s_setprio(1);
#pragma unroll
        for (int u = 0; u < 2; ++u)
#pragma unroll
            for (int nt = 0; nt < 4; ++nt)
                acc[u][nt] = __builtin_amdgcn_mfma_f32_16x16x32_bf16(Af[u].v, Bf[nt].v, acc[u][nt], 0, 0, 0);
        __builtin_amdgcn_s_setprio(0);
    }
    // ---- LayerNorm + full-line bf16 write to out_n[b][h][l][perm-d] ----
    {
        unsigned* outw = (unsigned*)out_n;
        size_t hb = ((size_t)b * 8 + h) * 64;
#pragma unroll
        for (int u = 0; u < 2; ++u)
#pragma unroll
            for (int i = 0; i < 4; ++i) {
                int l = 16 * (mt0 + u) + 4 * q + i;
                float v0 = acc[u][0][i], v1 = acc[u][1][i], v2 = acc[u][2][i], v3 = acc[u][3][i];
                float s1 = v0 + v1 + v2 + v3;
                float s2 = v0 * v0 + v1 * v1 + v2 * v2 + v3 * v3;
                s1 += __shfl_xor(s1, 1); s2 += __shfl_xor(s2, 1);
                s1 += __shfl_xor(s1, 2); s2 += __shfl_xor(s2, 2);
                s1 += __shfl_xor(s1, 4); s2 += __shfl_xor(s2, 4);
                s1 += __shfl_xor(s1, 8); s2 += __shfl_xor(s2, 8);
                float mu = s1 * (1.0f / 64.0f);
                float var = s2 * (1.0f / 64.0f) - mu * mu;
                float rstd = __builtin_amdgcn_rsqf(var + 1e-5f);
                float cmu = -mu * rstd;
                float y0 = fmaf(fmaf(v0, rstd, cmu), gvv[0], bvv[0]);
                float y1 = fmaf(fmaf(v1, rstd, cmu), gvv[1], bvv[1]);
                float y2 = fmaf(fmaf(v2, rstd, cmu), gvv[2], bvv[2]);
                float y3 = fmaf(fmaf(v3, rstd, cmu), gvv[3], bvv[3]);
                packline(outw + (hb + l) * 32, c, y0, y1, y2, y3);
            }
    }
}

// ---------------------------------------------------------------------------
// Kernel D (MFMA): per b. Stage 16-l chunks of out_n[b][h][l][perm-d] into LDS
// transposed as XT[l][d][h] (pad 8, perm-d undone via m^48 block remap).
// Staging: xor-pair dword packing + next-chunk register prefetch.
// C_l[d][o] = X_l[d,h] @ W1^T (K=8 pad 32, b1 folded into k=8 slot).
// g[b,d,o] = (1/cnt) * sum_{valid l} relu(C_l). 4 waves = quadrants.
// ---------------------------------------------------------------------------
__global__ __launch_bounds__(256) void k_mlp(const int* __restrict__ inputs,
                                             const unsigned short* __restrict__ out_n,
                                             const float* __restrict__ W1,
                                             const float* __restrict__ b1,
                                             float* __restrict__ gws) {
    __shared__ unsigned short XT[8320]; // 16 rows * 520 u16 (row pad 8)
    __shared__ unsigned long long vmask_s;
    __shared__ float invcnt_s;
    int t = threadIdx.x, w = t >> 6, lane = t & 63;
    int b = blockIdx.x;
    int ot = w >> 1, dt = w & 1;
    int kq = lane >> 4, n = lane & 15;

    if (t < 64) {
        int tok = inputs[b * 64 + t];
        unsigned long long bal = __ballot(tok != 0);
        if (t == 0) {
            int cnt = __popcll(bal);
            if (cnt < 1) cnt = 1;
            vmask_s = bal;
            invcnt_s = 1.0f / (float)cnt;
        }
    }

    // B-frags: W1 rows o = 32*ot + 16*om + n, k=h on kq==0 lanes; k=8 -> b1[o]
    FragU Wf[2];
#pragma unroll
    for (int om = 0; om < 2; ++om) {
        int o = 32 * ot + 16 * om + n;
        if (kq == 0) {
            const float4* wsrc = (const float4*)(W1 + o * 8);
            float4 wa = wsrc[0], wb = wsrc[1];
            Wf[om].u.x = (unsigned)f2bf(wa.x) | ((unsigned)f2bf(wa.y) << 16);
            Wf[om].u.y = (unsigned)f2bf(wa.z) | ((unsigned)f2bf(wa.w) << 16);
            Wf[om].u.z = (unsigned)f2bf(wb.x) | ((unsigned)f2bf(wb.y) << 16);
            Wf[om].u.w = (unsigned)f2bf(wb.z) | ((unsigned)f2bf(wb.w) << 16);
        } else if (kq == 1) {
            Wf[om].u = make_uint4((unsigned)f2bf(b1[o]), 0, 0, 0); // B[8][o] = b1[o]
        } else {
            Wf[om].u = make_uint4(0, 0, 0, 0);
        }
    }

    f32x4 racc[2][2];
    const f32x4 zf = {0.f, 0.f, 0.f, 0.f};
#pragma unroll
    for (int dm = 0; dm < 2; ++dm)
#pragma unroll
        for (int om = 0; om < 2; ++om) racc[dm][om] = zf;

    int lh = t & 7;          // h for the load phase
    int lr = (t >> 3) & 15;  // l-within-chunk
    int half = t >> 7;       // stored-d half

    // per-thread base of its load stream; chunk cc = +cc*128 uint4
    const uint4* src4 = (const uint4*)(out_n + (size_t)b * 32768 + lh * 4096
                                       + lr * 64 + half * 32);
    uint4 G[4], Gn[4];
#pragma unroll
    for (int j = 0; j < 4; ++j) G[j] = src4[j];   // prefetch chunk 0

    int c2 = lh >> 1, lodd = lh & 1;
    unsigned* XTd = (unsigned*)XT;
    int dbase = lr * 260 + c2;

    __syncthreads();
    unsigned long long vmask = vmask_s;
    float invcnt = invcnt_s;

    for (int cc = 0; cc < 4; ++cc) {
        __syncthreads(); // previous chunk's compute done before overwrite
        // ---- stage G -> XT via xor-pair dword packing ----
#pragma unroll
        for (int j = 0; j < 4; ++j) {
            int m0 = half * 32 + j * 8;                       // stored index
            int d0 = (m0 >= 16 && m0 < 48) ? (m0 ^ 48) : m0;  // actual d
            unsigned wv[4] = {G[j].x, G[j].y, G[j].z, G[j].w};
#pragma unroll
            for (int i = 0; i < 4; ++i) {
                unsigned pw = __shfl_xor(wv[i], 1);
                unsigned val = lodd ? ((pw >> 16) | (wv[i] & 0xffff0000u))
                                    : ((wv[i] & 0xffffu) | (pw << 16));
                int d = d0 + 2 * i + lodd;
                XTd[dbase + d * 4] = val;
            }
        }
        // ---- prefetch next chunk (hides L2/L3 latency under compute) ----
        if (cc < 3) {
#pragma unroll
            for (int j = 0; j < 4; ++j) Gn[j] = src4[(cc + 1) * 128 + j];
        }
        __syncthreads();
#pragma unroll 4
        for (int l = 0; l < 16; ++l) {
            if (!((vmask >> (16 * cc + l)) & 1ull)) continue; // pad token: skip (uniform)
            FragU Xf[2];
#pragma unroll
            for (int dm = 0; dm < 2; ++dm) {
                if (kq == 0)
                    Xf[dm].u = *(const uint4*)(XT + l * 520 + (32 * dt + 16 * dm + n) * 8);
                else if (kq == 1)
                    Xf[dm].u = make_uint4(0x3F80u, 0, 0, 0);  // A[d][8] = 1.0
                else
                    Xf[dm].u = make_uint4(0, 0, 0, 0);
            }
#pragma unroll
            for (int dm = 0; dm < 2; ++dm)
#pragma unroll
                for (int om = 0; om < 2; ++om) {
                    f32x4 C = __builtin_amdgcn_mfma_f32_16x16x32_bf16(Xf[dm].v, Wf[om].v, zf, 0, 0, 0);
#pragma unroll
                    for (int i = 0; i < 4; ++i)
                        racc[dm][om][i] += fmaxf(C[i], 0.0f);
                }
        }
        if (cc < 3) {
#pragma unroll
            for (int j = 0; j < 4; ++j) G[j] = Gn[j];
        }
    }
    // store: row d = 32dt+16dm+4*kq+i, col o = 32ot+16om+n
    float* gb = gws + (size_t)b * 4096;
#pragma unroll
    for (int dm = 0; dm < 2; ++dm)
#pragma unroll
        for (int om = 0; om < 2; ++om) {
            int o = 32 * ot + 16 * om + n;
#pragma unroll
            for (int i = 0; i < 4; ++i) {
                int d = 32 * dt + 16 * dm + 4 * kq + i;
                gb[d * 64 + o] = racc[dm][om][i] * invcnt;
            }
        }
}

// ---------------------------------------------------------------------------
// Kernel E: per name n: gbar = mean over 4 words; out = W2 @ gbar + b2
// ---------------------------------------------------------------------------
__global__ __launch_bounds__(256) void k_final(const float* __restrict__ gws,
                                               const float* __restrict__ W2,
                                               const float* __restrict__ b2,
                                               float* __restrict__ out) {
    __shared__ float gbar[4096];
    __shared__ float w2s[32 * 68];
    __shared__ float b2s[32];
    int t = threadIdx.x;
    int n = blockIdx.x;
    for (int e = t; e < 4096; e += 256) {
        size_t base = (size_t)(4 * n) * 4096 + e;
        gbar[e] = 0.25f * (gws[base] + gws[base + 4096] + gws[base + 8192] + gws[base + 12288]);
    }
    for (int e = t; e < 2048; e += 256) {
        int p = e >> 6, o = e & 63;
        w2s[p * 68 + o] = W2[e];
    }
    if (t < 32) b2s[t] = b2[t];
    __syncthreads();
#pragma unroll
    for (int jj = 0; jj < 8; ++jj) {
        int f = jj * 256 + t;
        int d = f >> 5, p = f & 31;
        float acc = b2s[p];
        for (int o4 = 0; o4 < 16; ++o4) {
            float4 gvv = *(const float4*)(gbar + d * 64 + o4 * 4);
            float4 wv = *(const float4*)(w2s + p * 68 + o4 * 4);
            acc = fmaf(gvv.x, wv.x, acc);
            acc = fmaf(gvv.y, wv.y, acc);
            acc = fmaf(gvv.z, wv.z, acc);
            acc = fmaf(gvv.w, wv.w, acc);
        }
        out[(size_t)n * 2048 + f] = acc;
    }
}

// ---------------------------------------------------------------------------
extern "C" void kernel_launch(void* const* d_in, const int* in_sizes, int n_in,
                              void* d_out, int out_size, void* d_ws, size_t ws_size,
                              hipStream_t stream) {
    const int*   inputs = (const int*)d_in[0];
    const float* W_emb  = (const float*)d_in[1];
    const float* W_qkv  = (const float*)d_in[2];
    const float* W_pos  = (const float*)d_in[3];
    const float* ln_g   = (const float*)d_in[4];
    const float* ln_b   = (const float*)d_in[5];
    const float* W1     = (const float*)d_in[6];
    const float* b1     = (const float*)d_in[7];
    const float* W2     = (const float*)d_in[8];
    const float* b2     = (const float*)d_in[9];
    float* out = (float*)d_out;

    // ws layout (u16 units unless noted): qkvb 6291456 | cst 4096 | csl 4096 |
    // wpos 4096 | gws fp32 8388608 | out_n u16 67108864
    unsigned short* qkvb = (unsigned short*)d_ws;
    unsigned short* cst  = qkvb + 6291456;
    unsigned short* csl  = cst + 4096;
    unsigned short* wpos = csl + 4096;
    float* gws = (float*)(wpos + 4096);
    unsigned short* out_n = (unsigned short*)(gws + 8388608);

    hipLaunchKernelGGL(k_qkv,   dim3(64 * 24), dim3(256), 0, stream, W_emb, W_qkv, qkvb);
    hipLaunchKernelGGL(k_tab,   dim3(16),      dim3(256), 0, stream, W_pos, cst, csl, wpos);
    hipLaunchKernelGGL(k_attn,  dim3(16384),   dim3(128), 0, stream,
                       inputs, qkvb, cst, csl, wpos, ln_g, ln_b, out_n);
    hipLaunchKernelGGL(k_mlp,   dim3(2048),    dim3(256), 0, stream, inputs, out_n, W1, b1, gws);
    hipLaunchKernelGGL(k_final, dim3(512),     dim3(256), 0, stream, gws, W2, b2, out);
}

// Round 10
// 349.175 us; speedup vs baseline: 1.2553x; 1.0223x over previous
//
#include <hip/hip_runtime.h>
#include <hip/hip_bf16.h>

// Problem constants: B=2048, L=64, V=4096, D=64, H=8, P=62

typedef __attribute__((ext_vector_type(8))) short short8;
typedef __attribute__((ext_vector_type(4))) float f32x4;

union FragU { uint4 u; short8 v; };

__device__ __forceinline__ unsigned short f2bf(float f) {
    union { float f; unsigned int i; } c; c.f = f;
    unsigned int i = c.i;
    unsigned int r = (i + 0x7fffu + ((i >> 16) & 1u)) >> 16;
    return (unsigned short)r;
}
__device__ __forceinline__ float asf(unsigned int u) {
    union { unsigned int i; float f; } c; c.i = u; return c.f;
}
__device__ __forceinline__ float bfsel(uint2 g, int i) {
    unsigned u = (i < 2) ? g.x : g.y;
    return asf((i & 1) ? (u & 0xffff0000u) : (u << 16));
}
// single-instruction packed f32->bf16 (RTNE), lo -> [15:0], hi -> [31:16]
__device__ __forceinline__ unsigned cvtpk(float lo, float hi) {
    unsigned r;
    asm("v_cvt_pk_bf16_f32 %0, %1, %2" : "=v"(r) : "v"(lo), "v"(hi));
    return r;
}

// xor-1 lane-pair pack: lane holds val[nt] for col 16*nt+c of row `rowptr`
// (36-dword padded LDS rows). Plain [col] u16 order across the 32-dword row.
__device__ __forceinline__ void packstore4(unsigned* rowptr, int c,
                                           float v0, float v1, float v2, float v3) {
    float p0 = __shfl_xor(v0, 1), p1 = __shfl_xor(v1, 1);
    float p2 = __shfl_xor(v2, 1), p3 = __shfl_xor(v3, 1);
    int odd = c & 1;
    float lo0 = odd ? p2 : v0, hi0 = odd ? v2 : p0;
    float lo1 = odd ? p3 : v1, hi1 = odd ? v3 : p1;
    unsigned a0 = cvtpk(lo0, hi0);
    unsigned a1 = cvtpk(lo1, hi1);
    int ba = (c >> 1) + (odd ? 16 : 0);
    rowptr[ba] = a0; rowptr[ba + 8] = a1;
}

// GLOBAL variant: full-64B-line-per-instruction slot mapping.
// store#1 (a0) -> dwords 0..15 (line 0 of the 128B row), store#2 (a1) -> 16..31.
// Stored u16 order within row: [cols 0..15 | 32..47 | 16..31 | 48..63],
// i.e. actual d = m ^ 48 for stored index m in [16,48), identity elsewhere.
__device__ __forceinline__ void packline(unsigned* rowbase, int c,
                                         float v0, float v1, float v2, float v3) {
    float p0 = __shfl_xor(v0, 1), p1 = __shfl_xor(v1, 1);
    float p2 = __shfl_xor(v2, 1), p3 = __shfl_xor(v3, 1);
    int odd = c & 1;
    float lo0 = odd ? p2 : v0, hi0 = odd ? v2 : p0;
    float lo1 = odd ? p3 : v1, hi1 = odd ? v3 : p1;
    unsigned a0 = cvtpk(lo0, hi0);
    unsigned a1 = cvtpk(lo1, hi1);
    int s = (c >> 1) + (odd ? 8 : 0);
    rowbase[s] = a0; rowbase[s + 16] = a1;
}

// ---------------------------------------------------------------------------
// Kernel A: qkv table = W_emb (4096x64) @ W_qkv^T -> bf16 (4096x1536).
// Q-slice (rt<8) pre-scaled by LAM = log2(e)/8 so k_attn's GEMM1 output is
// already log2-scaled (epilogue mul removed there).
// ---------------------------------------------------------------------------
__global__ __launch_bounds__(256) void k_qkv(const float* __restrict__ W_emb,
                                             const float* __restrict__ W_qkv,
                                             unsigned short* __restrict__ qkvb) {
    __shared__ float At[4096];
    __shared__ float Bt[4096];
    int t = threadIdx.x;
    int bt = blockIdx.x / 24, rt = blockIdx.x - bt * 24;
    int r = t >> 2, part = t & 3;
    const float4* esrc = (const float4*)(W_emb + (size_t)((bt << 6) + r) * 64 + part * 16);
    const float4* wsrc = (const float4*)(W_qkv + (size_t)((rt << 6) + r) * 64 + part * 16);
#pragma unroll
    for (int j = 0; j < 4; ++j) {
        float4 e4 = esrc[j], w4 = wsrc[j];
        int c0 = part * 16 + j * 4;
        At[(c0 + 0) * 64 + r] = e4.x; At[(c0 + 1) * 64 + r] = e4.y;
        At[(c0 + 2) * 64 + r] = e4.z; At[(c0 + 3) * 64 + r] = e4.w;
        Bt[(c0 + 0) * 64 + r] = w4.x; Bt[(c0 + 1) * 64 + r] = w4.y;
        Bt[(c0 + 2) * 64 + r] = w4.z; Bt[(c0 + 3) * 64 + r] = w4.w;
    }
    __syncthreads();
    int l0 = (t >> 4) << 2, m0 = (t & 15) << 2;
    float acc[4][4] = {};
#pragma unroll 4
    for (int k = 0; k < 64; ++k) {
        float4 a  = *(const float4*)(At + k * 64 + l0);
        float4 bb = *(const float4*)(Bt + k * 64 + m0);
        float aa[4] = {a.x, a.y, a.z, a.w};
        float bv[4] = {bb.x, bb.y, bb.z, bb.w};
#pragma unroll
        for (int i = 0; i < 4; ++i)
#pragma unroll
            for (int j = 0; j < 4; ++j)
                acc[i][j] = fmaf(aa[i], bv[j], acc[i][j]);
    }
    float qs = (rt < 8) ? 0.18033688f : 1.0f;   // LAM fold into Q slice
#pragma unroll
    for (int i = 0; i < 4; ++i) {
        unsigned w0 = (unsigned)f2bf(acc[i][0] * qs) | ((unsigned)f2bf(acc[i][1] * qs) << 16);
        unsigned w1 = (unsigned)f2bf(acc[i][2] * qs) | ((unsigned)f2bf(acc[i][3] * qs) << 16);
        unsigned* dst = (unsigned*)(qkvb + (size_t)((bt << 6) + l0 + i) * 1536 + (rt << 6) + m0);
        dst[0] = w0; dst[1] = w1;
    }
}

// ---------------------------------------------------------------------------
// Kernel B: trig + W_pos tables, padded 64-col layout, all bf16. Grid = 16.
// ---------------------------------------------------------------------------
__global__ void k_tab(const float* __restrict__ W_pos,
                      unsigned short* __restrict__ cst,
                      unsigned short* __restrict__ csl,
                      unsigned short* __restrict__ wpos) {
    int e = blockIdx.x * 256 + threadIdx.x;
    const float w = 6.283185307179586f / 63.0f;
    int row = e >> 6, col = e & 63;
    {
        int j = col, x = row;
        float val = 0.0f;
        if (j < 31)       val = cosf(w * (float)(((j + 1) * x) % 63));
        else if (j >= 32 && j < 63) val = sinf(w * (float)(((j - 31) * x) % 63));
        cst[e] = f2bf(val);
    }
    {
        int j = row, x = col;
        float val = 0.0f;
        if (j < 31)       val = cosf(w * (float)(((j + 1) * x) % 63));
        else if (j >= 32 && j < 63) val = sinf(w * (float)(((j - 31) * x) % 63));
        csl[e] = f2bf(val);
    }
    {
        int j = row;
        float val = 0.0f;
        if (j < 31) val = W_pos[j * 64 + col];
        else if (j >= 32 && j < 63) val = W_pos[(j - 1) * 64 + col];
        wpos[e] = f2bf(val);
    }
}

// ---------------------------------------------------------------------------
// Kernel C: fused attention (r5/r6 checkpoint — best verified; no setprio).
// Block = 2 waves = ONE (b,h); wave w2 owns row-half [32*w2, 32*w2+32).
// Pad-36 LDS rows, 18432 B -> 8 blocks/CU; VGPR-capped at 4 waves/SIMD
// (r8: 8 waves/SIMD forces spills; r1/r4: XOR-swizzle addressing forces
// spills; r9: setprio regresses — all reverted).
//   S0: Q -> SC -> ATTN      S1: K -> UW -> V^T
// Q pre-scaled by log2(e)/8 in qkvb -> GEMM1 output log2-scaled, softmax is
// a bare exp2. Pad tokens have zero embeddings -> zero K rows -> sim col 0.
// Output: contiguous [b][h][l][perm-d] bf16 rows, full-64B-line stores.
// ---------------------------------------------------------------------------
__global__ __launch_bounds__(128, 4) void k_attn(
    const int* __restrict__ inputs,
    const unsigned short* __restrict__ qkvb,
    const unsigned short* __restrict__ cstg,
    const unsigned short* __restrict__ cslg,
    const unsigned short* __restrict__ wposg,
    const float* __restrict__ ln_g,
    const float* __restrict__ ln_b,
    unsigned short* __restrict__ out_n)
{
    __shared__ __align__(16) unsigned int smem[4608]; // 18432 B
    unsigned int* S0d = smem;
    unsigned int* S1d = smem + 2304;
    int t = threadIdx.x, w2 = t >> 6, lane = t & 63;
    int b = blockIdx.x >> 3, h = blockIdx.x & 7;
    const int* toks = inputs + b * 64;
    int r = lane & 15, q = lane >> 4, c = r;
    int tk = toks[lane];
    int mt0 = 2 * w2;
    const float INV62 = 1.0f / 62.0f;

    int mk[4]; float gvv[4], bvv[4];
#pragma unroll
    for (int nt = 0; nt < 4; ++nt) {
        mk[nt] = (toks[16 * nt + c] == 0);
        gvv[nt] = ln_g[16 * nt + c];
        bvv[nt] = ln_b[16 * nt + c];
    }

    // ---- gather: wave0 -> Q into S0, wave1 -> K into S1 (lane = row) ----
    {
        const uint4* src = (const uint4*)(qkvb + (size_t)tk * 1536 + (w2 ? 512 : 0) + h * 64);
        uint4* dst = (uint4*)((w2 ? S1d : S0d) + lane * 36);
#pragma unroll
        for (int j = 0; j < 8; ++j) dst[j] = src[j];
    }
    __syncthreads(); // barrier 1

    f32x4 sc[2][4], acc[2][4];
    const f32x4 zf = {0.f, 0.f, 0.f, 0.f};

    // ---- GEMM1: sim = Q K^T (already log2-scaled via Q) ----
#pragma unroll
    for (int u = 0; u < 2; ++u)
#pragma unroll
        for (int nt = 0; nt < 4; ++nt) sc[u][nt] = zf;
#pragma unroll
    for (int ks = 0; ks < 2; ++ks) {
        FragU Af[2], Bf[4];
#pragma unroll
        for (int u = 0; u < 2; ++u)
            Af[u].u = *(const uint4*)(S0d + (16 * (mt0 + u) + r) * 36 + 16 * ks + 4 * q);
#pragma unroll
        for (int nt = 0; nt < 4; ++nt)
            Bf[nt].u = *(const uint4*)(S1d + (16 * nt + r) * 36 + 16 * ks + 4 * q);
#pragma unroll
        for (int u = 0; u < 2; ++u)
#pragma unroll
            for (int nt = 0; nt < 4; ++nt)
                sc[u][nt] = __builtin_amdgcn_mfma_f32_16x16x32_bf16(Af[u].v, Bf[nt].v, sc[u][nt], 0, 0, 0);
    }
    // epilogue 1: pure pack of SC -> S0 own rows (no mask/scale needed)
#pragma unroll
    for (int u = 0; u < 2; ++u)
#pragma unroll
        for (int i = 0; i < 4; ++i) {
            int l = 16 * (mt0 + u) + 4 * q + i;
            packstore4(S0d + l * 36, c, sc[u][0][i], sc[u][1][i], sc[u][2][i], sc[u][3][i]);
        }
    __syncthreads(); // barrier 2

    // ---- GEMM2: pos_w = SC @ Wpos^T + in-reg twist -> UW in S1 own rows ----
#pragma unroll
    for (int u = 0; u < 2; ++u)
#pragma unroll
        for (int nt = 0; nt < 4; ++nt) acc[u][nt] = zf;
#pragma unroll
    for (int ks = 0; ks < 2; ++ks) {
        FragU Af[2], Bf[4];
#pragma unroll
        for (int u = 0; u < 2; ++u)
            Af[u].u = *(const uint4*)(S0d + (16 * (mt0 + u) + r) * 36 + 16 * ks + 4 * q);
#pragma unroll
        for (int nt = 0; nt < 4; ++nt)
            Bf[nt].u = *(const uint4*)(wposg + (16 * nt + r) * 64 + 32 * ks + 8 * q);
#pragma unroll
        for (int u = 0; u < 2; ++u)
#pragma unroll
            for (int nt = 0; nt < 4; ++nt)
                acc[u][nt] = __builtin_amdgcn_mfma_f32_16x16x32_bf16(Af[u].v, Bf[nt].v, acc[u][nt], 0, 0, 0);
    }
#pragma unroll
    for (int u = 0; u < 2; ++u) {
        int mt = mt0 + u;
        uint2 t00 = *(const uint2*)(cslg + (c) * 64 + 16 * mt + 4 * q);
        uint2 t01 = *(const uint2*)(cslg + (32 + c) * 64 + 16 * mt + 4 * q);
        uint2 t10 = *(const uint2*)(cslg + (16 + c) * 64 + 16 * mt + 4 * q);
        uint2 t11 = *(const uint2*)(cslg + (48 + c) * 64 + 16 * mt + 4 * q);
#pragma unroll
        for (int i = 0; i < 4; ++i) {
            int l = 16 * mt + 4 * q + i;
            float cv0 = bfsel(t00, i), sv0 = bfsel(t01, i);
            float cv1 = bfsel(t10, i), sv1 = bfsel(t11, i);
            float pc0 = acc[u][0][i], ps0 = acc[u][2][i];
            float pc1 = acc[u][1][i], ps1 = acc[u][3][i];
            float u0 = pc0 * cv0 - ps0 * sv0;
            float u1 = pc1 * cv1 - ps1 * sv1;
            float u2 = pc0 * sv0 + ps0 * cv0;
            float u3 = pc1 * sv1 + ps1 * cv1;
            packstore4(S1d + l * 36, c, u0, u1, u2, u3);
        }
    }

    // ---- GEMM3: bias = UW @ CST^T ----
#pragma unroll
    for (int u = 0; u < 2; ++u)
#pragma unroll
        for (int nt = 0; nt < 4; ++nt) acc[u][nt] = zf;
#pragma unroll
    for (int ks = 0; ks < 2; ++ks) {
        FragU Af[2], Bf[4];
#pragma unroll
        for (int u = 0; u < 2; ++u)
            Af[u].u = *(const uint4*)(S1d + (16 * (mt0 + u) + r) * 36 + 16 * ks + 4 * q);
#pragma unroll
        for (int nt = 0; nt < 4; ++nt)
            Bf[nt].u = *(const uint4*)(cstg + (16 * nt + r) * 64 + 32 * ks + 8 * q);
#pragma unroll
        for (int u = 0; u < 2; ++u)
#pragma unroll
            for (int nt = 0; nt < 4; ++nt)
                acc[u][nt] = __builtin_amdgcn_mfma_f32_16x16x32_bf16(Af[u].v, Bf[nt].v, acc[u][nt], 0, 0, 0);
    }

    // ---- prefetch V half-row (own d-half, 64 B per lane) ----
    uint4 V4[4];
    {
        const uint4* vsrc = (const uint4*)(qkvb + (size_t)tk * 1536 + 1024 + h * 64 + 32 * w2);
#pragma unroll
        for (int j = 0; j < 4; ++j) V4[j] = vsrc[j];
    }

    // ---- softmax: x = SC(regs) + bias/62, already log2-scaled -> bare exp2 ----
#pragma unroll
    for (int u = 0; u < 2; ++u)
#pragma unroll
        for (int i = 0; i < 4; ++i) {
            int l = 16 * (mt0 + u) + 4 * q + i;
            float e0 = mk[0] ? 0.f : __builtin_amdgcn_exp2f(fmaf(acc[u][0][i], INV62, sc[u][0][i]));
            float e1 = mk[1] ? 0.f : __builtin_amdgcn_exp2f(fmaf(acc[u][1][i], INV62, sc[u][1][i]));
            float e2 = mk[2] ? 0.f : __builtin_amdgcn_exp2f(fmaf(acc[u][2][i], INV62, sc[u][2][i]));
            float e3 = mk[3] ? 0.f : __builtin_amdgcn_exp2f(fmaf(acc[u][3][i], INV62, sc[u][3][i]));
            float s = e0 + e1 + e2 + e3;
            s += __shfl_xor(s, 1);
            s += __shfl_xor(s, 2);
            s += __shfl_xor(s, 4);
            s += __shfl_xor(s, 8);
            float inv = __builtin_amdgcn_rcpf(s);
            packstore4(S0d + l * 36, c, e0 * inv, e1 * inv, e2 * inv, e3 * inv);
        }

    // ---- V^T scatter into S1 own d-half rows ----
    {
        int odd = lane & 1;
        const unsigned* Vd = (const unsigned*)V4;
#pragma unroll
        for (int jj = 0; jj < 16; ++jj) {
            unsigned my = Vd[jj];
            unsigned pr = __shfl_xor(my, 1);
            unsigned val = odd ? ((pr >> 16) | (my & 0xffff0000u))
                               : ((my & 0xffffu) | (pr << 16));
            S1d[(32 * w2 + 2 * jj + odd) * 36 + (lane >> 1)] = val;
        }
    }
    __syncthreads(); // barrier 3

    // ---- GEMM4: out = ATTN @ V ----
#pragma unroll
    for (int u = 0; u < 2; ++u)
#pragma unroll
        for (int nt = 0; nt < 4; ++nt) acc[u][nt] = zf;
#pragma unroll
    for (int ks = 0; ks < 2; ++ks) {
        FragU Af[2], Bf[4];
#pragma unroll
        for (int u = 0; u < 2; ++u)
            Af[u].u = *(const uint4*)(S0d + (16 * (mt0 + u) + r) * 36 + 16 * ks + 4 * q);
#pragma unroll
        for (int nt = 0; nt < 4; ++nt)
            Bf[nt].u = *(const uint4*)(S1d + (16 * nt + r) * 36 + 16 * ks + 4 * q);
#pragma unroll
        for (int u = 0; u < 2; ++u)
#pragma unroll
            for (int nt = 0; nt < 4; ++nt)
                acc[u][nt] = __builtin_amdgcn_mfma_f32_16x16x32_bf16(Af[u].v, Bf[nt].v, acc[u][nt], 0, 0, 0);
    }
    // ---- LayerNorm + full-line bf16 write to out_n[b][h][l][perm-d] ----
    {
        unsigned* outw = (unsigned*)out_n;
        size_t hb = ((size_t)b * 8 + h) * 64;
#pragma unroll
        for (int u = 0; u < 2; ++u)
#pragma unroll
            for (int i = 0; i < 4; ++i) {
                int l = 16 * (mt0 + u) + 4 * q + i;
                float v0 = acc[u][0][i], v1 = acc[u][1][i], v2 = acc[u][2][i], v3 = acc[u][3][i];
                float s1 = v0 + v1 + v2 + v3;
                float s2 = v0 * v0 + v1 * v1 + v2 * v2 + v3 * v3;
                s1 += __shfl_xor(s1, 1); s2 += __shfl_xor(s2, 1);
                s1 += __shfl_xor(s1, 2); s2 += __shfl_xor(s2, 2);
                s1 += __shfl_xor(s1, 4); s2 += __shfl_xor(s2, 4);
                s1 += __shfl_xor(s1, 8); s2 += __shfl_xor(s2, 8);
                float mu = s1 * (1.0f / 64.0f);
                float var = s2 * (1.0f / 64.0f) - mu * mu;
                float rstd = __builtin_amdgcn_rsqf(var + 1e-5f);
                float cmu = -mu * rstd;
                float y0 = fmaf(fmaf(v0, rstd, cmu), gvv[0], bvv[0]);
                float y1 = fmaf(fmaf(v1, rstd, cmu), gvv[1], bvv[1]);
                float y2 = fmaf(fmaf(v2, rstd, cmu), gvv[2], bvv[2]);
                float y3 = fmaf(fmaf(v3, rstd, cmu), gvv[3], bvv[3]);
                packline(outw + (hb + l) * 32, c, y0, y1, y2, y3);
            }
    }
}

// ---------------------------------------------------------------------------
// Kernel D (MFMA): per b. Stage 16-l chunks of out_n[b][h][l][perm-d] into LDS
// transposed as XT[l][d][h] (pad 8, perm-d undone via m^48 block remap).
// Staging: xor-pair dword packing + next-chunk register prefetch.
// C_l[d][o] = X_l[d,h] @ W1^T (K=8 pad 32, b1 folded into k=8 slot).
// g[b,d,o] = (1/cnt) * sum_{valid l} relu(C_l). 4 waves = quadrants.
// ---------------------------------------------------------------------------
__global__ __launch_bounds__(256) void k_mlp(const int* __restrict__ inputs,
                                             const unsigned short* __restrict__ out_n,
                                             const float* __restrict__ W1,
                                             const float* __restrict__ b1,
                                             float* __restrict__ gws) {
    __shared__ unsigned short XT[8320]; // 16 rows * 520 u16 (row pad 8)
    __shared__ unsigned long long vmask_s;
    __shared__ float invcnt_s;
    int t = threadIdx.x, w = t >> 6, lane = t & 63;
    int b = blockIdx.x;
    int ot = w >> 1, dt = w & 1;
    int kq = lane >> 4, n = lane & 15;

    if (t < 64) {
        int tok = inputs[b * 64 + t];
        unsigned long long bal = __ballot(tok != 0);
        if (t == 0) {
            int cnt = __popcll(bal);
            if (cnt < 1) cnt = 1;
            vmask_s = bal;
            invcnt_s = 1.0f / (float)cnt;
        }
    }

    // B-frags: W1 rows o = 32*ot + 16*om + n, k=h on kq==0 lanes; k=8 -> b1[o]
    FragU Wf[2];
#pragma unroll
    for (int om = 0; om < 2; ++om) {
        int o = 32 * ot + 16 * om + n;
        if (kq == 0) {
            const float4* wsrc = (const float4*)(W1 + o * 8);
            float4 wa = wsrc[0], wb = wsrc[1];
            Wf[om].u.x = (unsigned)f2bf(wa.x) | ((unsigned)f2bf(wa.y) << 16);
            Wf[om].u.y = (unsigned)f2bf(wa.z) | ((unsigned)f2bf(wa.w) << 16);
            Wf[om].u.z = (unsigned)f2bf(wb.x) | ((unsigned)f2bf(wb.y) << 16);
            Wf[om].u.w = (unsigned)f2bf(wb.z) | ((unsigned)f2bf(wb.w) << 16);
        } else if (kq == 1) {
            Wf[om].u = make_uint4((unsigned)f2bf(b1[o]), 0, 0, 0); // B[8][o] = b1[o]
        } else {
            Wf[om].u = make_uint4(0, 0, 0, 0);
        }
    }

    f32x4 racc[2][2];
    const f32x4 zf = {0.f, 0.f, 0.f, 0.f};
#pragma unroll
    for (int dm = 0; dm < 2; ++dm)
#pragma unroll
        for (int om = 0; om < 2; ++om) racc[dm][om] = zf;

    int lh = t & 7;          // h for the load phase
    int lr = (t >> 3) & 15;  // l-within-chunk
    int half = t >> 7;       // stored-d half

    // per-thread base of its load stream; chunk cc = +cc*128 uint4
    const uint4* src4 = (const uint4*)(out_n + (size_t)b * 32768 + lh * 4096
                                       + lr * 64 + half * 32);
    uint4 G[4], Gn[4];
#pragma unroll
    for (int j = 0; j < 4; ++j) G[j] = src4[j];   // prefetch chunk 0

    int c2 = lh >> 1, lodd = lh & 1;
    unsigned* XTd = (unsigned*)XT;
    int dbase = lr * 260 + c2;

    __syncthreads();
    unsigned long long vmask = vmask_s;
    float invcnt = invcnt_s;

    for (int cc = 0; cc < 4; ++cc) {
        __syncthreads(); // previous chunk's compute done before overwrite
        // ---- stage G -> XT via xor-pair dword packing ----
#pragma unroll
        for (int j = 0; j < 4; ++j) {
            int m0 = half * 32 + j * 8;                       // stored index
            int d0 = (m0 >= 16 && m0 < 48) ? (m0 ^ 48) : m0;  // actual d
            unsigned wv[4] = {G[j].x, G[j].y, G[j].z, G[j].w};
#pragma unroll
            for (int i = 0; i < 4; ++i) {
                unsigned pw = __shfl_xor(wv[i], 1);
                unsigned val = lodd ? ((pw >> 16) | (wv[i] & 0xffff0000u))
                                    : ((wv[i] & 0xffffu) | (pw << 16));
                int d = d0 + 2 * i + lodd;
                XTd[dbase + d * 4] = val;
            }
        }
        // ---- prefetch next chunk (hides L2/L3 latency under compute) ----
        if (cc < 3) {
#pragma unroll
            for (int j = 0; j < 4; ++j) Gn[j] = src4[(cc + 1) * 128 + j];
        }
        __syncthreads();
#pragma unroll 4
        for (int l = 0; l < 16; ++l) {
            if (!((vmask >> (16 * cc + l)) & 1ull)) continue; // pad token: skip (uniform)
            FragU Xf[2];
#pragma unroll
            for (int dm = 0; dm < 2; ++dm) {
                if (kq == 0)
                    Xf[dm].u = *(const uint4*)(XT + l * 520 + (32 * dt + 16 * dm + n) * 8);
                else if (kq == 1)
                    Xf[dm].u = make_uint4(0x3F80u, 0, 0, 0);  // A[d][8] = 1.0
                else
                    Xf[dm].u = make_uint4(0, 0, 0, 0);
            }
#pragma unroll
            for (int dm = 0; dm < 2; ++dm)
#pragma unroll
                for (int om = 0; om < 2; ++om) {
                    f32x4 C = __builtin_amdgcn_mfma_f32_16x16x32_bf16(Xf[dm].v, Wf[om].v, zf, 0, 0, 0);
#pragma unroll
                    for (int i = 0; i < 4; ++i)
                        racc[dm][om][i] += fmaxf(C[i], 0.0f);
                }
        }
        if (cc < 3) {
#pragma unroll
            for (int j = 0; j < 4; ++j) G[j] = Gn[j];
        }
    }
    // store: row d = 32dt+16dm+4*kq+i, col o = 32ot+16om+n
    float* gb = gws + (size_t)b * 4096;
#pragma unroll
    for (int dm = 0; dm < 2; ++dm)
#pragma unroll
        for (int om = 0; om < 2; ++om) {
            int o = 32 * ot + 16 * om + n;
#pragma unroll
            for (int i = 0; i < 4; ++i) {
                int d = 32 * dt + 16 * dm + 4 * kq + i;
                gb[d * 64 + o] = racc[dm][om][i] * invcnt;
            }
        }
}

// ---------------------------------------------------------------------------
// Kernel E: per name n: gbar = mean over 4 words; out = W2 @ gbar + b2
// ---------------------------------------------------------------------------
__global__ __launch_bounds__(256) void k_final(const float* __restrict__ gws,
                                               const float* __restrict__ W2,
                                               const float* __restrict__ b2,
                                               float* __restrict__ out) {
    __shared__ float gbar[4096];
    __shared__ float w2s[32 * 68];
    __shared__ float b2s[32];
    int t = threadIdx.x;
    int n = blockIdx.x;
    for (int e = t; e < 4096; e += 256) {
        size_t base = (size_t)(4 * n) * 4096 + e;
        gbar[e] = 0.25f * (gws[base] + gws[base + 4096] + gws[base + 8192] + gws[base + 12288]);
    }
    for (int e = t; e < 2048; e += 256) {
        int p = e >> 6, o = e & 63;
        w2s[p * 68 + o] = W2[e];
    }
    if (t < 32) b2s[t] = b2[t];
    __syncthreads();
#pragma unroll
    for (int jj = 0; jj < 8; ++jj) {
        int f = jj * 256 + t;
        int d = f >> 5, p = f & 31;
        float acc = b2s[p];
        for (int o4 = 0; o4 < 16; ++o4) {
            float4 gvv = *(const float4*)(gbar + d * 64 + o4 * 4);
            float4 wv = *(const float4*)(w2s + p * 68 + o4 * 4);
            acc = fmaf(gvv.x, wv.x, acc);
            acc = fmaf(gvv.y, wv.y, acc);
            acc = fmaf(gvv.z, wv.z, acc);
            acc = fmaf(gvv.w, wv.w, acc);
        }
        out[(size_t)n * 2048 + f] = acc;
    }
}

// ---------------------------------------------------------------------------
extern "C" void kernel_launch(void* const* d_in, const int* in_sizes, int n_in,
                              void* d_out, int out_size, void* d_ws, size_t ws_size,
                              hipStream_t stream) {
    const int*   inputs = (const int*)d_in[0];
    const float* W_emb  = (const float*)d_in[1];
    const float* W_qkv  = (const float*)d_in[2];
    const float* W_pos  = (const float*)d_in[3];
    const float* ln_g   = (const float*)d_in[4];
    const float* ln_b   = (const float*)d_in[5];
    const float* W1     = (const float*)d_in[6];
    const float* b1     = (const float*)d_in[7];
    const float* W2     = (const float*)d_in[8];
    const float* b2     = (const float*)d_in[9];
    float* out = (float*)d_out;

    // ws layout (u16 units unless noted): qkvb 6291456 | cst 4096 | csl 4096 |
    // wpos 4096 | gws fp32 8388608 | out_n u16 67108864
    unsigned short* qkvb = (unsigned short*)d_ws;
    unsigned short* cst  = qkvb + 6291456;
    unsigned short* csl  = cst + 4096;
    unsigned short* wpos = csl + 4096;
    float* gws = (float*)(wpos + 4096);
    unsigned short* out_n = (unsigned short*)(gws + 8388608);

    hipLaunchKernelGGL(k_qkv,   dim3(64 * 24), dim3(256), 0, stream, W_emb, W_qkv, qkvb);
    hipLaunchKernelGGL(k_tab,   dim3(16),      dim3(256), 0, stream, W_pos, cst, csl, wpos);
    hipLaunchKernelGGL(k_attn,  dim3(16384),   dim3(128), 0, stream,
                       inputs, qkvb, cst, csl, wpos, ln_g, ln_b, out_n);
    hipLaunchKernelGGL(k_mlp,   dim3(2048),    dim3(256), 0, stream, inputs, out_n, W1, b1, gws);
    hipLaunchKernelGGL(k_final, dim3(512),     dim3(256), 0, stream, gws, W2, b2, out);
}